// Round 1
// baseline (651.388 us; speedup 1.0000x reference)
//
#include <hip/hip_runtime.h>

// MeanAggregator: out[b,:] = mean over {neighbours[b,0..9], nodes[b]} of features[idx,:]
// B=100000, K=10, N=1000000, D=128. Pure memory-bound gather.
//
// Layout: one 64-lane wave per node; each lane holds float2 (64*8B = 512B = one
// full feature row per vector load instruction). 4 nodes per 256-thread block.

#define KNEIGH 10
#define DDIM 128

__global__ __launch_bounds__(256) void MeanAggregator_36386962932386_kernel(
    const int* __restrict__ nodes,
    const int* __restrict__ neighbours,
    const float* __restrict__ features,
    float* __restrict__ out,
    int B)
{
    const int node = blockIdx.x * 4 + (threadIdx.x >> 6);
    if (node >= B) return;
    const int lane = threadIdx.x & 63;

    // Gather all 11 row indices into registers first (uniform-per-wave loads,
    // served by L1/L2 broadcast; tiny traffic).
    int idx[KNEIGH + 1];
    const long long nb = (long long)node * KNEIGH;
#pragma unroll
    for (int j = 0; j < KNEIGH; ++j) idx[j] = neighbours[nb + j];
    idx[KNEIGH] = nodes[node];

    // Issue all 11 independent feature loads (compiler keeps them in flight),
    // then accumulate.
    float2 v[KNEIGH + 1];
#pragma unroll
    for (int j = 0; j < KNEIGH + 1; ++j) {
        const float2* row = (const float2*)(features + (long long)idx[j] * DDIM);
        v[j] = row[lane];
    }

    float2 acc = v[0];
#pragma unroll
    for (int j = 1; j < KNEIGH + 1; ++j) {
        acc.x += v[j].x;
        acc.y += v[j].y;
    }

    const float s = 1.0f / (float)(KNEIGH + 1);
    float2 o;
    o.x = acc.x * s;
    o.y = acc.y * s;
    ((float2*)(out + (long long)node * DDIM))[lane] = o;
}

extern "C" void kernel_launch(void* const* d_in, const int* in_sizes, int n_in,
                              void* d_out, int out_size, void* d_ws, size_t ws_size,
                              hipStream_t stream)
{
    const int* nodes      = (const int*)d_in[0];
    const int* neighbours = (const int*)d_in[1];
    const float* features = (const float*)d_in[2];
    float* out            = (float*)d_out;

    const int B = in_sizes[0];           // 100000
    const int blocks = (B + 3) / 4;      // 4 nodes per 256-thread block

    MeanAggregator_36386962932386_kernel<<<blocks, 256, 0, stream>>>(
        nodes, neighbours, features, out, B);
}